// Round 1
// baseline (394.059 us; speedup 1.0000x reference)
//
#include <hip/hip_runtime.h>
#include <math.h>

#define BATCH 32
#define NROWS 4096
#define CDIM  512
#define EPS_INV 10.0f   // 1/EPS_SINKHORN

// ---------------------------------------------------------------------------
// Pass 1: fused l2norm + similarity + exp-weight + weighted accumulation.
// Grid: (CHUNKS, BATCH), block = 256 threads = 4 waves.
// Each wave owns rows [row0, row0+RPW) with half-wave ownership:
//   lanes 0-31  -> even rows of the pair   (lane: 4x float4 = cols 4hl+{0,128,256,384})
//   lanes 32-63 -> odd rows
// Loop body processes TWO pairs (rows A and B per half-wave) with an explicit
// 2-deep register pipeline: next group's 8 dwordx4 loads are issued before the
// current group's dot/butterfly chain, keeping >=8 load instrs in flight/wave.
// Butterfly reduce: 5 steps over 32 lanes, 4 independent chains (sA,qA,sB,qB).
// ---------------------------------------------------------------------------

#define LOAD4(d0,d1,d2,d3, ptr) do {                \
    d0 = *(const float4*)((ptr) + cb);              \
    d1 = *(const float4*)((ptr) + 128 + cb);        \
    d2 = *(const float4*)((ptr) + 256 + cb);        \
    d3 = *(const float4*)((ptr) + 384 + cb); } while (0)

#define DOT16(x0,x1,x2,x3, y0,y1,y2,y3)             \
    ( x0.x*y0.x + x0.y*y0.y + x0.z*y0.z + x0.w*y0.w \
    + x1.x*y1.x + x1.y*y1.y + x1.z*y1.z + x1.w*y1.w \
    + x2.x*y2.x + x2.y*y2.y + x2.z*y2.z + x2.w*y2.w \
    + x3.x*y3.x + x3.y*y3.y + x3.z*y3.z + x3.w*y3.w )

template<int CHUNKS>
__global__ __launch_bounds__(256, 4) void uot_pass1(
    const float* __restrict__ prompt,     // [BATCH, CDIM]
    const float* __restrict__ vf,         // [BATCH, NROWS, CDIM]
    float* __restrict__ ws_acc,           // [BATCH*CHUNKS, CDIM]
    float* __restrict__ ws_l)             // [BATCH*CHUNKS]
{
    constexpr int RPC    = NROWS / CHUNKS;   // rows per chunk
    constexpr int RPW    = RPC / 4;          // rows per wave
    constexpr int PAIRS  = RPW / 2;          // row-pairs per wave
    constexpr int GROUPS = PAIRS / 2;        // 2 pairs per loop body

    const int b     = blockIdx.y;
    const int chunk = blockIdx.x;
    const int lane  = threadIdx.x & 63;
    const int wave  = threadIdx.x >> 6;
    const int half  = lane >> 5;          // 0 or 1: which row of the pair
    const int hl    = lane & 31;
    const int cb    = 4 * hl;             // column base within each 128-col band

    // ---- normalized prompt fragment: lane owns cols cb + {0,128,256,384} ----
    const float* pp = prompt + (size_t)b * CDIM;
    float4 p0, p1, p2, p3;
    LOAD4(p0, p1, p2, p3, pp);
    float ss = DOT16(p0,p1,p2,p3, p0,p1,p2,p3);
    #pragma unroll
    for (int off = 16; off > 0; off >>= 1) ss += __shfl_xor(ss, off);
    const float pinv = 1.0f / fmaxf(sqrtf(ss), 1e-12f);
    p0.x *= pinv; p0.y *= pinv; p0.z *= pinv; p0.w *= pinv;
    p1.x *= pinv; p1.y *= pinv; p1.z *= pinv; p1.w *= pinv;
    p2.x *= pinv; p2.y *= pinv; p2.z *= pinv; p2.w *= pinv;
    p3.x *= pinv; p3.y *= pinv; p3.z *= pinv; p3.w *= pinv;

    float4 a0 = make_float4(0.f,0.f,0.f,0.f), a1 = a0, a2 = a0, a3 = a0;
    float  lsum = 0.f;   // sum of weights over THIS half's rows only

    const int row0 = chunk * RPC + wave * RPW;
    const float* __restrict__ base =
        vf + ((size_t)b * NROWS + row0 + half) * CDIM;

    // register pipeline: cur group (pairs A,B) + next group prefetch
    float4 cA0,cA1,cA2,cA3, cB0,cB1,cB2,cB3;
    float4 nA0,nA1,nA2,nA3, nB0,nB1,nB2,nB3;
    LOAD4(cA0,cA1,cA2,cA3, base);                       // pair it=0  -> row off 0
    LOAD4(cB0,cB1,cB2,cB3, base + 2 * CDIM);            // pair it=1  -> row off 2

    #pragma unroll
    for (int g = 0; g < GROUPS; ++g) {
        // ---- prefetch next group's two rows (issues before any compute) ----
        if (g + 1 < GROUPS) {
            const float* nx = base + (size_t)(4 * (g + 1)) * CDIM;
            LOAD4(nA0,nA1,nA2,nA3, nx);
            LOAD4(nB0,nB1,nB2,nB3, nx + 2 * CDIM);
        }

        // ---- dot products (pure FMA on registers already in flight) ----
        float sA = DOT16(cA0,cA1,cA2,cA3, p0,p1,p2,p3);
        float qA = DOT16(cA0,cA1,cA2,cA3, cA0,cA1,cA2,cA3);
        float sB = DOT16(cB0,cB1,cB2,cB3, p0,p1,p2,p3);
        float qB = DOT16(cB0,cB1,cB2,cB3, cB0,cB1,cB2,cB3);

        // ---- 5-step butterfly within each 32-lane half, 4 indep chains ----
        #pragma unroll
        for (int off = 16; off > 0; off >>= 1) {
            sA += __shfl_xor(sA, off);
            qA += __shfl_xor(qA, off);
            sB += __shfl_xor(sB, off);
            qB += __shfl_xor(qB, off);
        }

        const float invA = rsqrtf(fmaxf(qA, 1e-24f));
        const float invB = rsqrtf(fmaxf(qB, 1e-24f));
        // logits in [-20, 0]: exp never overflows, no max-subtraction needed
        const float wA = __expf((sA * invA - 1.0f) * EPS_INV);
        const float wB = __expf((sB * invB - 1.0f) * EPS_INV);
        const float winA = wA * invA;
        const float winB = wB * invB;

        a0.x += winA*cA0.x + winB*cB0.x;  a0.y += winA*cA0.y + winB*cB0.y;
        a0.z += winA*cA0.z + winB*cB0.z;  a0.w += winA*cA0.w + winB*cB0.w;
        a1.x += winA*cA1.x + winB*cB1.x;  a1.y += winA*cA1.y + winB*cB1.y;
        a1.z += winA*cA1.z + winB*cB1.z;  a1.w += winA*cA1.w + winB*cB1.w;
        a2.x += winA*cA2.x + winB*cB2.x;  a2.y += winA*cA2.y + winB*cB2.y;
        a2.z += winA*cA2.z + winB*cB2.z;  a2.w += winA*cA2.w + winB*cB2.w;
        a3.x += winA*cA3.x + winB*cB3.x;  a3.y += winA*cA3.y + winB*cB3.y;
        a3.z += winA*cA3.z + winB*cB3.z;  a3.w += winA*cA3.w + winB*cB3.w;
        lsum += wA + wB;

        // rotate pipeline (renamed away by the full unroll)
        cA0=nA0; cA1=nA1; cA2=nA2; cA3=nA3;
        cB0=nB0; cB1=nB1; cB2=nB2; cB3=nB3;
    }

    // ---- cross-group reduction via LDS: 8 groups (4 waves x 2 halves) ----
    __shared__ float lds_acc[8][CDIM];
    __shared__ float lds_l[8];
    const int g = wave * 2 + half;
    *(float4*)&lds_acc[g][cb]       = a0;
    *(float4*)&lds_acc[g][128 + cb] = a1;
    *(float4*)&lds_acc[g][256 + cb] = a2;
    *(float4*)&lds_acc[g][384 + cb] = a3;
    if (hl == 0) lds_l[g] = lsum;
    __syncthreads();

    const int t = threadIdx.x;
    float s0 = 0.f, s1 = 0.f;
    #pragma unroll
    for (int gg = 0; gg < 8; ++gg) {
        s0 += lds_acc[gg][t];
        s1 += lds_acc[gg][t + 256];
    }
    const size_t blk = (size_t)b * CHUNKS + chunk;
    ws_acc[blk * CDIM + t]       = s0;
    ws_acc[blk * CDIM + t + 256] = s1;
    if (t == 0) {
        float L = 0.f;
        #pragma unroll
        for (int gg = 0; gg < 8; ++gg) L += lds_l[gg];
        ws_l[blk] = L;
    }
}

// ---------------------------------------------------------------------------
// Pass 2: fold per-chunk partials, apply softmax denom + mass normalization.
// Grid: BATCH blocks, 256 threads. Thread t handles cols t and t+256.
// ---------------------------------------------------------------------------
__global__ __launch_bounds__(256) void uot_pass2(
    const float* __restrict__ ws_acc,
    const float* __restrict__ ws_l,
    const float* __restrict__ dustbin_param,
    float* __restrict__ out,              // [BATCH*CDIM] obs, then [BATCH] mass
    int chunks)
{
    const int b = blockIdx.x;
    const int t = threadIdx.x;
    float s0 = 0.f, s1 = 0.f, L = 0.f;
    #pragma unroll 4
    for (int k = 0; k < chunks; ++k) {
        const size_t base = ((size_t)b * chunks + k) * CDIM;
        s0 += ws_acc[base + t];
        s1 += ws_acc[base + t + 256];
        L  += ws_l[(size_t)b * chunks + k];
    }
    const float denom = L + __expf(-dustbin_param[0] * EPS_INV);
    const float tm    = L / denom;
    const float scale = 1.0f / (denom * (tm + 1e-6f));
    out[(size_t)b * CDIM + t]       = s0 * scale;
    out[(size_t)b * CDIM + t + 256] = s1 * scale;
    if (t == 0) out[(size_t)BATCH * CDIM + b] = tm;
}

extern "C" void kernel_launch(void* const* d_in, const int* in_sizes, int n_in,
                              void* d_out, int out_size, void* d_ws, size_t ws_size,
                              hipStream_t stream) {
    const float* prompt        = (const float*)d_in[0];  // (32,1,512)
    const float* vf            = (const float*)d_in[1];  // (32,4096,512)
    // d_in[2] = dustbin_token — unused by the reference computation
    const float* dustbin_param = (const float*)d_in[3];  // (1,)
    float* out = (float*)d_out;

    // chunks=32 -> 1024 blocks = exactly 4 blocks/CU (one residency round at
    // <=128 VGPR via __launch_bounds__(256,4)). Fallbacks for tiny workspace.
    auto need = [](int c) {
        return ((size_t)BATCH * c * CDIM + (size_t)BATCH * c) * sizeof(float);
    };
    float* ws_acc = (float*)d_ws;
    int chunks;
    if (ws_size >= need(32)) {
        chunks = 32;
        float* ws_l = ws_acc + (size_t)BATCH * chunks * CDIM;
        uot_pass1<32><<<dim3(chunks, BATCH), 256, 0, stream>>>(prompt, vf, ws_acc, ws_l);
        uot_pass2<<<BATCH, 256, 0, stream>>>(ws_acc, ws_l, dustbin_param, out, chunks);
    } else if (ws_size >= need(8)) {
        chunks = 8;
        float* ws_l = ws_acc + (size_t)BATCH * chunks * CDIM;
        uot_pass1<8><<<dim3(chunks, BATCH), 256, 0, stream>>>(prompt, vf, ws_acc, ws_l);
        uot_pass2<<<BATCH, 256, 0, stream>>>(ws_acc, ws_l, dustbin_param, out, chunks);
    } else {
        chunks = 1;
        float* ws_l = ws_acc + (size_t)BATCH * chunks * CDIM;
        uot_pass1<1><<<dim3(chunks, BATCH), 256, 0, stream>>>(prompt, vf, ws_acc, ws_l);
        uot_pass2<<<BATCH, 256, 0, stream>>>(ws_acc, ws_l, dustbin_param, out, chunks);
    }
}